// Round 17
// baseline (296.341 us; speedup 1.0000x reference)
//
#include <hip/hip_runtime.h>
#include <stdint.h>

#define TT 2048
#define EE 2048
#define HH 16
#define DD 128

static constexpr float F_EPS = 1e-5f;
// 128^-0.5 * log2(e): Q pre-scaled into log2 domain so softmax exp is a bare v_exp_f32
static constexpr float F_SCAL_L2E = (float)(0.08838834764831845 * 1.4426950408889634);

using f32x4  = __attribute__((ext_vector_type(4))) float;
using bf16x8 = __attribute__((ext_vector_type(8))) short;
using u16x8  = __attribute__((ext_vector_type(8))) unsigned short;
using i32x4  = __attribute__((ext_vector_type(4))) int;

#define MFMA_BF16(a,b,c) __builtin_amdgcn_mfma_f32_16x16x32_bf16((a),(b),(c),0,0,0)
#define MFMA_I8(a,b,c)   __builtin_amdgcn_mfma_i32_16x16x64_i8((a),(b),(c),0,0,0)

#define GLD16(gp, lp) __builtin_amdgcn_global_load_lds( \
    (__attribute__((address_space(1))) void*)(unsigned long long)(gp), \
    (__attribute__((address_space(3))) void*)(lp), 16, 0, 0)

__device__ __forceinline__ unsigned short f2bf(float x){
  unsigned u = __float_as_uint(x);
  u = (u + 0x7FFFu + ((u >> 16) & 1u)) >> 16;
  return (unsigned short)u;
}
__device__ __forceinline__ float bf2f(unsigned short h){
  return __uint_as_float(((unsigned)h) << 16);
}
// bare HW exp2 (v_exp_f32: D = 2^S0); args are in log2 domain already
__device__ __forceinline__ float exp2_hw(float x){
  float r;
  asm("v_exp_f32 %0, %1" : "=v"(r) : "v"(x));
  return r;
}
// full-block max reduce (leading sync makes it reusable)
__device__ __forceinline__ float blockmax(float am, float* red, int tid){
  __syncthreads();
  #pragma unroll
  for (int o=1;o<64;o<<=1) am = fmaxf(am, __shfl_xor(am, o));
  if ((tid&63)==0) red[tid>>6] = am;
  __syncthreads();
  return fmaxf(fmaxf(red[0],red[1]), fmaxf(red[2],red[3]));
}

// chunk enumeration: per head, 80 blocks cover the causal triangle with <=8 tiles each
__device__ __forceinline__ void cid_map(int cid, int& qt, int& ch, int& nc){
  if (cid < 8)       { qt = cid;                ch = 0;            nc = 1; }
  else if (cid < 24) { qt = 8  + ((cid-8)>>1);  ch = (cid-8)&1;    nc = 2; }
  else if (cid < 48) { qt = 16 + (cid-24)/3;    ch = (cid-24)%3;   nc = 3; }
  else               { qt = 24 + ((cid-48)>>2); ch = (cid-48)&3;   nc = 4; }
}
__device__ __forceinline__ int aoff(int qt){   // lp2 slot offset (all chunks)
  return (qt<16) ? 2*(qt-8) : ((qt<24) ? 16+3*(qt-16) : 40+4*(qt-24));
}
__device__ __forceinline__ int aoff2(int qt){  // Opart slot offset (ch>=1 only)
  return (qt<16) ? (qt-8) : ((qt<24) ? 8+2*(qt-16) : 24+3*(qt-24));
}
// XCD head-affinity remap: all blocks of one head share flat%8 => same XCD slot
__device__ __forceinline__ void attn_remap(int& h, int& cid){
  const int flat = blockIdx.y*80 + blockIdx.x;
  const int j = flat & 15;
  h = (j & 7)*2 + (j >> 3);
  cid = flat >> 4;
}

// ---- LDS staging with XOR swizzle (byte ^= (row&7)<<4) on global src + reads (bf16)
__device__ __forceinline__ void stage_k64x128(const unsigned short* gbase, unsigned short* lds, int tid){
  const char* gb = (const char*)gbase;
  char* lb = (char*)lds;
  #pragma unroll
  for (int i=0;i<4;i++){
    const int idx = i*256 + tid;
    const int r = idx >> 4, c = idx & 15;
    GLD16(gb + (size_t)r*(EE*2) + (unsigned)((c*16) ^ ((r&7)<<4)), lb + idx*16);
  }
}
__device__ __forceinline__ void stage_v128x64(const unsigned short* gbase, unsigned short* lds, int tid){
  const char* gb = (const char*)gbase;
  char* lb = (char*)lds;
  #pragma unroll
  for (int i=0;i<4;i++){
    const int idx = i*256 + tid;
    const int r = idx >> 3, c = idx & 7;
    GLD16(gb + (size_t)r*(TT*2) + (unsigned)((c*16) ^ ((r&7)<<4)), lb + idx*16);
  }
}
__device__ __forceinline__ bf16x8 frag_k(const unsigned short* lds, int kr, int dbyte){
  return *(const bf16x8*)((const char*)lds + kr*256 + (dbyte ^ ((kr&7)<<4)));
}
__device__ __forceinline__ bf16x8 frag_v(const unsigned short* lds, int dr, int kbyte){
  return *(const bf16x8*)((const char*)lds + dr*128 + (kbyte ^ ((dr&7)<<4)));
}

// ------- fused row quantization: hs + 4 weights -> int8 (+ sv_bits zeroing) --------
__global__ __launch_bounds__(256) void k_quant5(
    const float* __restrict__ hs, const float* __restrict__ qwf,
    const float* __restrict__ kwf, const float* __restrict__ vwf,
    const float* __restrict__ owf,
    char* __restrict__ qx, char* __restrict__ qw4,
    float* __restrict__ sx, float* __restrict__ sw,
    unsigned* __restrict__ sv_bits)
{
  __shared__ float red[4];
  const int which = blockIdx.x >> 11;
  const int row = blockIdx.x & (TT-1);
  const int tid = threadIdx.x;
  if (blockIdx.x < 8) sv_bits[blockIdx.x*256 + tid] = 0u;   // zero before k_colmax
  const float* in; char* outq; float* outs;
  if      (which==0){ in=hs;  outq=qx;                   outs=sx;      }
  else if (which==1){ in=qwf; outq=qw4;                  outs=sw;      }
  else if (which==2){ in=kwf; outq=qw4+(size_t)EE*EE;    outs=sw+EE;   }
  else if (which==3){ in=vwf; outq=qw4+(size_t)2*EE*EE;  outs=sw+2*EE; }
  else              { in=owf; outq=qw4+(size_t)3*EE*EE;  outs=sw+3*EE; }
  const float* r = in + (size_t)row * EE;
  float x[8];
  {
    const f32x4 a = *(const f32x4*)(r + tid*8);
    const f32x4 b = *(const f32x4*)(r + tid*8 + 4);
    x[0]=a[0]; x[1]=a[1]; x[2]=a[2]; x[3]=a[3];
    x[4]=b[0]; x[5]=b[1]; x[6]=b[2]; x[7]=b[3];
  }
  float am = 0.f;
  #pragma unroll
  for (int j=0;j<8;j++) am = fmaxf(am, fabsf(x[j]));
  am = blockmax(am, red, tid);
  const float s = fmaxf(am, F_EPS) / 127.f;
  if (tid==0) outs[row] = s;
  union { char c[8]; int2 v; } u;
  #pragma unroll
  for (int j=0;j<8;j++) u.c[j] = (char)(int)rintf(x[j]/s);
  *(int2*)(outq + (size_t)row*EE + tid*8) = u.v;
}

// generic single-array int8 row quant (for ctx)
__global__ __launch_bounds__(256) void k_rowquant8(
    const float* __restrict__ in, char* __restrict__ outq, float* __restrict__ outs)
{
  __shared__ float red[4];
  const int row = blockIdx.x;
  const int tid = threadIdx.x;
  const float* r = in + (size_t)row * EE;
  float x[8];
  {
    const f32x4 a = *(const f32x4*)(r + tid*8);
    const f32x4 b = *(const f32x4*)(r + tid*8 + 4);
    x[0]=a[0]; x[1]=a[1]; x[2]=a[2]; x[3]=a[3];
    x[4]=b[0]; x[5]=b[1]; x[6]=b[2]; x[7]=b[3];
  }
  float am = 0.f;
  #pragma unroll
  for (int j=0;j<8;j++) am = fmaxf(am, fabsf(x[j]));
  am = blockmax(am, red, tid);
  const float s = fmaxf(am, F_EPS) / 127.f;
  if (tid==0) outs[row] = s;
  union { char c[8]; int2 v; } u;
  #pragma unroll
  for (int j=0;j<8;j++) u.c[j] = (char)(int)rintf(x[j]/s);
  *(int2*)(outq + (size_t)row*EE + tid*8) = u.v;
}

// mixed K quantization (bf16-int out for attn2 MFMA) + per-row dequant slice norm
__global__ __launch_bounds__(256) void k_quant_kmixed(
    const float* __restrict__ kin, const int* __restrict__ imp,
    unsigned short* __restrict__ qkm, float* __restrict__ sk,
    float* __restrict__ kmn)
{
  __shared__ float red[4];
  const int row = blockIdx.x;
  const int tid = threadIdx.x;
  const float* r = kin + (size_t)row * EE;
  float x[8];
  {
    const f32x4 a = *(const f32x4*)(r + tid*8);
    const f32x4 b = *(const f32x4*)(r + tid*8 + 4);
    x[0]=a[0]; x[1]=a[1]; x[2]=a[2]; x[3]=a[3];
    x[4]=b[0]; x[5]=b[1]; x[6]=b[2]; x[7]=b[3];
  }
  float am = 0.f;
  #pragma unroll
  for (int j=0;j<8;j++) am = fmaxf(am, fabsf(x[j]));
  am = blockmax(am, red, tid);
  float s;
  if (imp[row]) s = fmaxf(am / 127.f, F_EPS);
  else          s = fmaxf(am, F_EPS) / 7.f;
  if (tid==0) sk[row] = s;
  u16x8 qv;
  float ss = 0.f;
  #pragma unroll
  for (int j=0;j<8;j++){
    const float p = rintf(x[j]/s);
    qv[j] = f2bf(p);
    const float dq = p*s;
    ss += dq*dq;
  }
  *(u16x8*)(qkm + (size_t)row*EE + tid*8) = qv;
  ss += __shfl_xor(ss,1); ss += __shfl_xor(ss,2);
  ss += __shfl_xor(ss,4); ss += __shfl_xor(ss,8);
  const float mx = blockmax(ss, red, tid);
  if (tid==0) kmn[row] = __builtin_sqrtf(mx);
}

// ---- fused norms: q hi/lo slice norm, k slice norm, v row dq-scale ----
__global__ __launch_bounds__(256) void k_norm3(
    const unsigned short* __restrict__ qhi, const unsigned short* __restrict__ qlo,
    const float* __restrict__ kbuf, const float* __restrict__ vbuf,
    float* __restrict__ qn, float* __restrict__ kn, float* __restrict__ sdq)
{
  __shared__ float red[4];
  const int which = blockIdx.x >> 11;
  const int row = blockIdx.x & (TT-1);
  const int tid = threadIdx.x;
  if (which == 0){
    const u16x8 h = *(const u16x8*)(qhi + (size_t)row*EE + tid*8);
    const u16x8 l = *(const u16x8*)(qlo + (size_t)row*EE + tid*8);
    float ss = 0.f;
    #pragma unroll
    for (int j=0;j<8;j++){
      const float v = bf2f(h[j]) + bf2f(l[j]);
      ss += v*v;
    }
    ss += __shfl_xor(ss,1); ss += __shfl_xor(ss,2);
    ss += __shfl_xor(ss,4); ss += __shfl_xor(ss,8);
    const float mx = blockmax(ss, red, tid);
    if (tid==0) qn[row] = __builtin_sqrtf(mx);
  } else if (which == 1){
    const f32x4 a = *(const f32x4*)(kbuf + (size_t)row*EE + tid*8);
    const f32x4 b = *(const f32x4*)(kbuf + (size_t)row*EE + tid*8 + 4);
    float ss = a[0]*a[0]+a[1]*a[1]+a[2]*a[2]+a[3]*a[3]
             + b[0]*b[0]+b[1]*b[1]+b[2]*b[2]+b[3]*b[3];
    ss += __shfl_xor(ss,1); ss += __shfl_xor(ss,2);
    ss += __shfl_xor(ss,4); ss += __shfl_xor(ss,8);
    const float mx = blockmax(ss, red, tid);
    if (tid==0) kn[row] = __builtin_sqrtf(mx);
  } else {
    const f32x4 a = *(const f32x4*)(vbuf + (size_t)row*EE + tid*8);
    const f32x4 b = *(const f32x4*)(vbuf + (size_t)row*EE + tid*8 + 4);
    float am = fmaxf(fmaxf(fmaxf(fabsf(a[0]),fabsf(a[1])), fmaxf(fabsf(a[2]),fabsf(a[3]))),
                     fmaxf(fmaxf(fabsf(b[0]),fabsf(b[1])), fmaxf(fabsf(b[2]),fabsf(b[3]))));
    am = blockmax(am, red, tid);
    if (tid==0) sdq[row] = fmaxf(am, F_EPS) / 127.f;
  }
}

__global__ __launch_bounds__(256) void k_redmax2(
    const float* __restrict__ a, const float* __restrict__ b, float* __restrict__ dst)
{
  const float* s = blockIdx.x ? b : a;
  const int tid = threadIdx.x;
  float m = 0.f;
  #pragma unroll
  for (int i=0;i<8;i++) m = fmaxf(m, s[tid + i*256]);
  #pragma unroll
  for (int o=1;o<64;o<<=1) m = fmaxf(m, __shfl_xor(m,o));
  __shared__ float red[4];
  if ((tid&63)==0) red[tid>>6]=m;
  __syncthreads();
  if (tid==0) dst[blockIdx.x] = fmaxf(fmaxf(red[0],red[1]), fmaxf(red[2],red[3]));
}

// ------------- int8 GEMM core: 128x128 tile, BK=128, exact i32 dot -----------------
// LDS rows are 128 B: full XOR swizzle byte ^= (row&7)<<4 (2-way alias = free),
// applied on pre-swizzled global source (GLD16 writes LDS linearly) and on reads.
__device__ __forceinline__ void gemm8_body(
    const char* __restrict__ Aq, const float* __restrict__ sa,
    const char* __restrict__ Bq, const float* __restrict__ sb,
    const float* __restrict__ bias, float post,
    float* __restrict__ Cout, unsigned short* __restrict__ Hout,
    unsigned short* __restrict__ Lout,
    char* lA, char* lB)
{
  const int tid = threadIdx.x;
  const int bm = blockIdx.y, bn = blockIdx.x;
  const int lane = tid & 63, w = tid >> 6;
  const int wr = w >> 1, wc = w & 1;           // wave grid 2x2, each 64x64 output
  i32x4 acc[4][4];
  const i32x4 IZ = {0,0,0,0};
  #pragma unroll
  for (int i=0;i<4;i++)
    #pragma unroll
    for (int j=0;j<4;j++) acc[i][j] = IZ;

  const char* gA = Aq + (size_t)(bm*128)*EE;
  const char* gB = Bq + (size_t)(bn*128)*EE;

  for (int k0 = 0; k0 < EE; k0 += 128) {
    #pragma unroll
    for (int i=0;i<4;i++){
      const int c = i*256 + tid;               // A: 1024 chunks (128 rows x 8)
      const int rr = c >> 3, k16 = c & 7;
      GLD16(gA + (size_t)rr*EE + k0 + ((k16*16) ^ ((rr&7)<<4)), lA + c*16);
    }
    #pragma unroll
    for (int i=0;i<4;i++){
      const int c = i*256 + tid;               // B: 1024 chunks (128 rows x 8)
      const int rr = c >> 3, k16 = c & 7;
      GLD16(gB + (size_t)rr*EE + k0 + ((k16*16) ^ ((rr&7)<<4)), lB + c*16);
    }
    __syncthreads();
    #pragma unroll
    for (int ks=0;ks<2;ks++){
      i32x4 af[4], bf[4];
      #pragma unroll
      for (int mi=0;mi<4;mi++){
        const int rr = wr*64 + mi*16 + (lane&15);
        const int off = ks*64 + ((lane>>4)*16);
        af[mi] = *(const i32x4*)(lA + rr*128 + (off ^ ((rr&7)<<4)));
      }
      #pragma unroll
      for (int ni=0;ni<4;ni++){
        const int rr = wc*64 + ni*16 + (lane&15);
        const int off = ks*64 + ((lane>>4)*16);
        bf[ni] = *(const i32x4*)(lB + rr*128 + (off ^ ((rr&7)<<4)));
      }
      #pragma unroll
      for (int mi=0;mi<4;mi++)
        #pragma unroll
        for (int ni=0;ni<4;ni++)
          acc[mi][ni] = MFMA_I8(af[mi], bf[ni], acc[mi][ni]);
    }
    __syncthreads();
  }
  const int row0 = bm*128 + wr*64;
  const int col0 = bn*128 + wc*64;
  #pragma unroll
  for (int mi=0;mi<4;mi++){
    #pragma unroll
    for (int r=0;r<4;r++){
      const int row = row0 + mi*16 + (lane>>4)*4 + r;
      const float sav = sa[row];
      #pragma unroll
      for (int ni=0;ni<4;ni++){
        const int col = col0 + ni*16 + (lane&15);
        const float v = ((float)acc[mi][ni][r]*sav*sb[col] + bias[col]) * post;
        if (Cout) Cout[(size_t)row*EE + col] = v;
        if (Hout){
          const unsigned short hh = f2bf(v);
          Hout[(size_t)row*EE + col] = hh;
          if (Lout) Lout[(size_t)row*EE + col] = f2bf(v - bf2f(hh));
        }
      }
    }
  }
}

__global__ __launch_bounds__(256) void k_gemm8_qkv(
    const char* __restrict__ Aq, const float* __restrict__ sa,
    const char* __restrict__ qw4, const float* __restrict__ sw,
    const float* __restrict__ q_b, const float* __restrict__ k_b,
    const float* __restrict__ v_b,
    float* __restrict__ kbuf, float* __restrict__ vbuf,
    unsigned short* __restrict__ q_hi, unsigned short* __restrict__ q_lo,
    unsigned short* __restrict__ k_hi)
{
  __shared__ char lA[128*128];
  __shared__ char lB[128*128];
  const int z = blockIdx.z;
  const char* Bq = qw4 + (size_t)z*EE*EE;
  const float* sb = sw + z*EE;
  const float* bias = (z==0) ? q_b : (z==1) ? k_b : v_b;
  const float post = (z==0) ? F_SCAL_L2E : 1.f;   // Q carries scaling*log2(e)
  float* Cout = (z==1) ? kbuf : (z==2) ? vbuf : nullptr;
  unsigned short* Hout = (z==0) ? q_hi : (z==1) ? k_hi : nullptr;
  unsigned short* Lout = (z==0) ? q_lo : nullptr;
  gemm8_body(Aq, sa, Bq, sb, bias, post, Cout, Hout, Lout, lA, lB);
}

__global__ __launch_bounds__(256) void k_gemm8_one(
    const char* __restrict__ Aq, const float* __restrict__ sa,
    const char* __restrict__ Bq, const float* __restrict__ sb,
    const float* __restrict__ bias, float* __restrict__ Cout)
{
  __shared__ char lA[128*128];
  __shared__ char lB[128*128];
  gemm8_body(Aq, sa, Bq, sb, bias, 1.f, Cout, nullptr, nullptr, lA, lB);
}

// ---------------- V per-column quant (dq on the fly) ----------------
__global__ __launch_bounds__(256) void k_colmax(
    const float* __restrict__ v, const float* __restrict__ sdq,
    unsigned* __restrict__ sv_bits)
{
  const int e = blockIdx.x*256 + threadIdx.x;
  const int t0 = blockIdx.y*64;
  float am = 0.f;
  for (int t=t0; t<t0+64; ++t){
    const float s = sdq[t];
    const float dq = rintf(v[(size_t)t*EE + e]/s)*s;
    am = fmaxf(am, fabsf(dq));
  }
  atomicMax(sv_bits + e, __float_as_uint(am));
}

__global__ __launch_bounds__(256) void k_vq_transpose(
    const float* __restrict__ v, const float* __restrict__ sdq,
    const unsigned* __restrict__ sv_bits,
    float* __restrict__ sv, unsigned short* __restrict__ qvT)
{
  __shared__ unsigned short tile[64][66];
  const int t0 = blockIdx.x*64, e0 = blockIdx.y*64;
  const int tid = threadIdx.x;
  {
    const int ee = tid & 63, tb = (tid>>6)*16;
    const float sve = fmaxf(__uint_as_float(sv_bits[e0+ee]), F_EPS) / 127.f;
    for (int i=0;i<16;i++){
      const int t = t0+tb+i;
      const float s = sdq[t];
      const float dq = rintf(v[(size_t)t*EE + e0+ee]/s)*s;
      tile[tb+i][ee] = f2bf(rintf(dq / sve));
    }
  }
  if (blockIdx.x==0 && tid<64)
    sv[e0+tid] = fmaxf(__uint_as_float(sv_bits[e0+tid]), F_EPS) / 127.f;
  __syncthreads();
  {
    const int ttl = tid & 63, ebl = (tid>>6)*16;
    for (int i=0;i<16;i++)
      qvT[(size_t)(e0+ebl+i)*TT + t0+ttl] = tile[ttl][ebl+i];
  }
}

// ---- attention pass 1: chunked denominators (swapped QK^T: S[key][query]) ---------
__global__ __launch_bounds__(256) void k_attn1_stats(
    const unsigned short* __restrict__ qh, const unsigned short* __restrict__ ql,
    const unsigned short* __restrict__ kh,
    const float* __restrict__ nbv, float* __restrict__ lp)
{
  __shared__ unsigned short lKh[64*128];
  int h, cid; attn_remap(h, cid);
  int qt, ch, nc; cid_map(cid, qt, ch, nc);
  const int per = (qt + nc)/nc;
  const int s0 = ch*per, s1 = min(s0+per-1, qt);
  const int tid = threadIdx.x, w = tid>>6, lane = tid&63;
  const int row_base = qt*64 + w*16, lrow = (lane>>4)*4;
  const float B1 = nbv[0] * nbv[1] * 1.001f + 1e-3f;
  bf16x8 qhf[4], qlf[4];
  {
    const size_t qo = (size_t)(row_base + (lane&15))*EE + h*DD + (lane>>4)*8;
    #pragma unroll
    for (int kc=0;kc<4;kc++){
      qhf[kc] = *(const bf16x8*)(qh + qo + kc*32);
      qlf[kc] = *(const bf16x8*)(ql + qo + kc*32);
    }
  }
  const int query = row_base + (lane&15);
  float l_acc = 0.f;
  stage_k64x128(kh + (size_t)(s0*64)*EE + h*DD, lKh, tid);
  for (int st=s0; st<=s1; ++st){
    __syncthreads();
    f32x4 S[4];
    #pragma unroll
    for (int n=0;n<4;n++){
      f32x4 a = {0.f,0.f,0.f,0.f};
      const int kr = n*16 + (lane&15);
      #pragma unroll
      for (int kc=0;kc<4;kc++){
        const int db = kc*64 + (lane>>4)*16;
        const bf16x8 khf = frag_k(lKh, kr, db);
        a = MFMA_BF16(khf, qhf[kc], a);
        a = MFMA_BF16(khf, qlf[kc], a);
      }
      S[n] = a;
    }
    __syncthreads();
    if (st < s1)
      stage_k64x128(kh + (size_t)((st+1)*64)*EE + h*DD, lKh, tid);
    float ls = 0.f;
    if (st == qt){                       // diagonal tile: causal masking needed
      #pragma unroll
      for (int n=0;n<4;n++){
        #pragma unroll
        for (int r=0;r<4;r++){
          const int key = st*64 + n*16 + lrow + r;
          ls += (key<=query) ? exp2_hw(S[n][r]-B1) : 0.f;
        }
      }
    } else {                             // fully below diagonal: all keys valid
      #pragma unroll
      for (int n=0;n<4;n++){
        #pragma unroll
        for (int r=0;r<4;r++)
          ls += exp2_hw(S[n][r]-B1);
      }
    }
    ls += __shfl_xor(ls,16);
    ls += __shfl_xor(ls,32);
    l_acc += ls;
  }
  if (lane < 16){
    const int slot = (h*80 + cid)*64;
    lp[slot + w*16 + lane] = l_acc;
  }
}

__global__ __launch_bounds__(64) void k_stats_combine(
    const float* __restrict__ lp, float* __restrict__ il1)
{
  const int qt = blockIdx.x, h = blockIdx.y, r = threadIdx.x;
  const int nc  = (qt<8)?1:((qt<16)?2:((qt<24)?3:4));
  const int off = (qt<8)?qt:((qt<16)?8+2*(qt-8):((qt<24)?24+3*(qt-16):48+4*(qt-24)));
  const int base = (h*80 + off)*64 + r;
  float l = 0.f;
  for (int i=0;i<nc;i++) l += lp[base + i*64];
  il1[h*TT + qt*64 + r] = 1.f/l;
}

// ---------------- attention pass 1b: column sums (2-MFMA, K-hi only) ---------------
__global__ __launch_bounds__(256) void k_attn1_acc(
    const unsigned short* __restrict__ qh, const unsigned short* __restrict__ ql,
    const unsigned short* __restrict__ kh,
    const float* __restrict__ nbv, const float* __restrict__ il1,
    float* __restrict__ partial)
{
  __shared__ unsigned short lKh[64*128];
  __shared__ float accw[4][512];
  int h, cid; attn_remap(h, cid);
  int qt, ch, nc; cid_map(cid, qt, ch, nc);
  const int per = (qt + nc)/nc;
  const int s0 = ch*per, s1 = min(s0+per-1, qt);
  const int tid = threadIdx.x, w = tid>>6, lane = tid&63;
  const int row_base = qt*64 + w*16, lrow = (lane>>4)*4;
  const float B1 = nbv[0] * nbv[1] * 1.001f + 1e-3f;
  bf16x8 qhf[4], qlf[4];
  {
    const size_t qo = (size_t)(row_base + (lane&15))*EE + h*DD + (lane>>4)*8;
    #pragma unroll
    for (int kc=0;kc<4;kc++){
      qhf[kc] = *(const bf16x8*)(qh + qo + kc*32);
      qlf[kc] = *(const bf16x8*)(ql + qo + kc*32);
    }
  }
  float il_r[4];
  #pragma unroll
  for (int r=0;r<4;r++)
    il_r[r] = il1[h*TT + row_base + lrow + r];
  stage_k64x128(kh + (size_t)(s0*64)*EE + h*DD, lKh, tid);
  for (int st=s0; st<=s1; ++st){
    __syncthreads();
    f32x4 S[4];
    #pragma unroll
    for (int n=0;n<4;n++){
      f32x4 a = {0.f,0.f,0.f,0.f};
      const int kr = n*16 + (lane&15);
      #pragma unroll
      for (int kc=0;kc<4;kc++){
        const int db = kc*64 + (lane>>4)*16;
        const bf16x8 khf = frag_k(lKh, kr, db);
        a = MFMA_BF16(qhf[kc], khf, a);
        a = MFMA_BF16(qlf[kc], khf, a);
      }
      S[n] = a;
    }
    __syncthreads();
    if (st < s1)
      stage_k64x128(kh + (size_t)((st+1)*64)*EE + h*DD, lKh, tid);
    if (st == qt){                       // diagonal tile: causal masking needed
      #pragma unroll
      for (int n=0;n<4;n++){
        const int col = st*64 + n*16 + (lane&15);
        float cs = 0.f;
        #pragma unroll
        for (int r=0;r<4;r++){
          const int row = row_base + lrow + r;
          cs += (col<=row) ? exp2_hw(S[n][r]-B1)*il_r[r] : 0.f;
        }
        cs += __shfl_xor(cs,16);
        cs += __shfl_xor(cs,32);
        if (lane < 16) accw[w][(st-s0)*64 + n*16 + lane] = cs;
      }
    } else {
      #pragma unroll
      for (int n=0;n<4;n++){
        float cs = 0.f;
        #pragma unroll
        for (int r=0;r<4;r++)
          cs += exp2_hw(S[n][r]-B1)*il_r[r];
        cs += __shfl_xor(cs,16);
        cs += __shfl_xor(cs,32);
        if (lane < 16) accw[w][(st-s0)*64 + n*16 + lane] = cs;
      }
    }
  }
  __syncthreads();
  const int ncols = (s1-s0+1)*64;
  float* dst = partial + (size_t)(h*32+qt)*TT + s0*64;
  for (int i=tid; i<ncols; i+=256)
    dst[i] = accw[0][i]+accw[1][i]+accw[2][i]+accw[3][i];
}

// ---------------- acc reduce + rank-count top-51 selection ----------------
__global__ __launch_bounds__(256) void k_accsum(
    const float* __restrict__ partial, float* __restrict__ acc16)
{
  const int s = blockIdx.x*256 + threadIdx.x;
  const int hh = blockIdx.y;
  const int tmin = s >> 6;
  float a = 0.f;
  for (int qt=tmin; qt<32; ++qt)
    a += partial[(size_t)(hh*32+qt)*TT + s];
  acc16[hh*TT + s] = a;
}

__global__ __launch_bounds__(512) void k_select(
    const float* __restrict__ acc16, int* __restrict__ imp)
{
  __shared__ float vals[512];
  const int tid = threadIdx.x;
  const int s = blockIdx.x*512 + tid;
  float a = 0.f;
  #pragma unroll
  for (int hh=0; hh<16; ++hh) a += acc16[hh*TT + s];
  a = a / (float)(TT - s) / 16.f;
  vals[tid] = a;
  __syncthreads();
  int rank = 0;
  for (int j=0; j<512; ++j){
    const float vj = vals[j];
    rank += (vj > a) || (vj == a && j < tid);
  }
  imp[s] = (rank < 51) ? 1 : 0;
}

// ------ attention pass 2: chunked flash, dbuf K/V, l via ones-MFMA on P ------------
__global__ __launch_bounds__(256) void k_attn2(
    const unsigned short* __restrict__ qh, const unsigned short* __restrict__ ql,
    const unsigned short* __restrict__ qkm, const float* __restrict__ sk,
    const unsigned short* __restrict__ qvT, const float* __restrict__ sv,
    const float* __restrict__ nbv,
    float* __restrict__ ctx, float* __restrict__ lp2,
    unsigned short* __restrict__ Opart)
{
  __shared__ unsigned short lKA[64*128];
  __shared__ unsigned short lVA[128*64];
  __shared__ unsigned short lKB[64*128];
  __shared__ unsigned short lVB[128*64];
  __shared__ unsigned short Ph[4][16*64];
  int h, cid; attn_remap(h, cid);
  int qt, ch, nc; cid_map(cid, qt, ch, nc);
  const int per = (qt + nc)/nc;
  const int s0 = ch*per, s1 = min(s0+per-1, qt);
  const int tid = threadIdx.x, w = tid>>6, lane = tid&63;
  const int row_base = qt*64 + w*16, lrow = (lane>>4)*4;
  const float B2 = nbv[0] * nbv[2] * 1.001f + 1e-3f;
  unsigned short *curK = lKA, *curV = lVA, *nxtK = lKB, *nxtV = lVB;
  stage_k64x128(qkm + (size_t)(s0*64)*EE + h*DD, curK, tid);
  stage_v128x64(qvT + (size_t)(h*DD)*TT + s0*64, curV, tid);
  bf16x8 qhf[4], qlf[4];
  {
    const size_t qo = (size_t)(row_base + (lane&15))*EE + h*DD + (lane>>4)*8;
    #pragma unroll
    for (int kc=0;kc<4;kc++){
      qhf[kc] = *(const bf16x8*)(qh + qo + kc*32);
      qlf[kc] = *(const bf16x8*)(ql + qo + kc*32);
    }
  }
  const short ONE = (short)0x3F80;
  const bf16x8 ONESV = {ONE,ONE,ONE,ONE,ONE,ONE,ONE,ONE};
  f32x4 lsum;
  f32x4 oa[8];
  const f32x4 FZ = {0.f,0.f,0.f,0.f};
  lsum = FZ;
  #pragma unroll
  for (int d8=0; d8<8; ++d8) oa[d8] = FZ;

  for (int st=s0; st<=s1; ++st){
    __syncthreads();                       // cur staged; drains prev prefetch
    if (st < s1){
      stage_k64x128(qkm + (size_t)((st+1)*64)*EE + h*DD, nxtK, tid);
      stage_v128x64(qvT + (size_t)(h*DD)*TT + (st+1)*64, nxtV, tid);
    }
    f32x4 S[4];
    #pragma unroll
    for (int n=0;n<4;n++){
      f32x4 a = {0.f,0.f,0.f,0.f};
      const int kr = n*16 + (lane&15);
      #pragma unroll
      for (int kc=0;kc<4;kc++){
        const int db = kc*64 + (lane>>4)*16;
        const bf16x8 kf = frag_k(curK, kr, db);
        a = MFMA_BF16(qhf[kc], kf, a);
        a = MFMA_BF16(qlf[kc], kf, a);
      }
      S[n] = a * sk[st*64 + n*16 + (lane&15)];
    }
    if (st == qt){                       // diagonal tile: causal masking needed
      #pragma unroll
      for (int r=0;r<4;r++){
        const int row = row_base + lrow + r;
        #pragma unroll
        for (int n=0;n<4;n++){
          const int col = st*64 + n*16 + (lane&15);
          const float pv = (col<=row) ? exp2_hw(S[n][r]-B2) : 0.f;
          *(unsigned short*)((char*)&Ph[w][0] + (lrow+r)*128 +
              ((((n*16 + (lane&15))*2)) ^ (((lrow+r)&7)<<4))) = f2bf(pv);
        }
      }
    } else {
      #pragma unroll
      for (int r=0;r<4;r++){
        #pragma unroll
        for (int n=0;n<4;n++){
          const float pv = exp2_hw(S[n][r]-B2);
          *(unsigned short*)((char*)&Ph[w][0] + (lrow+r)*128 +
              ((((n*16 + (lane&15))*2)) ^ (((lrow+r)&7)<<4))) = f2bf(pv);
        }
      }
    }
    // per-wave LDS write->read (in-wave lgkmcnt ordering)
    bf16x8 pah[2];
    #pragma unroll
    for (int kc=0;kc<2;kc++){
      const int rr = lane&15;
      const int cb = kc*64 + (lane>>4)*16;
      pah[kc] = *(const bf16x8*)((const char*)&Ph[w][0] + rr*128 + (cb ^ ((rr&7)<<4)));
    }
    // softmax denominator via ones-MFMA (consistent with bf16 P used in PV)
    lsum = MFMA_BF16(pah[0], ONESV, lsum);
    lsum = MFMA_BF16(pah[1], ONESV, lsum);
    #pragma unroll
    for (int d8=0; d8<8; ++d8){
      const int dr = d8*16 + (lane&15);
      const int kb = (lane>>4)*16;
      const bf16x8 v0 = frag_v(curV, dr, kb);
      const bf16x8 v1 = frag_v(curV, dr, kb + 64);
      oa[d8] = MFMA_BF16(pah[0], v0, oa[d8]);
      oa[d8] = MFMA_BF16(pah[1], v1, oa[d8]);
    }
    unsigned short* t;
    t = curK; curK = nxtK; nxtK = t;
    t = curV; curV = nxtV; nxtV = t;
  }
  if (nc == 1){
    #pragma unroll
    for (int d8=0; d8<8; ++d8){
      const float sve = sv[h*DD + d8*16 + (lane&15)];
      #pragma unroll
      for (int r=0;r<4;r++){
        const int row = row_base + lrow + r;
        ctx[(size_t)row*EE + h*DD + d8*16 + (lane&15)] = oa[d8][r]*sve/lsum[r];
      }
    }
  } else {
    const int slotl = h*72 + aoff(qt) + ch;
    if ((lane&15)==0){
      #pragma unroll
      for (int r=0;r<4;r++)
        lp2[slotl*64 + w*16 + lrow + r] = lsum[r];
    }
    if (ch == 0){
      #pragma unroll
      for (int d8=0; d8<8; ++d8){
        #pragma unroll
        for (int r=0;r<4;r++){
          const int row = row_base + lrow + r;
          ctx[(size_t)row*EE + h*DD + d8*16 + (lane&15)] = oa[d8][r];
        }
      }
    } else {
      const int slot = h*48 + aoff2(qt) + (ch-1);
      #pragma unroll
      for (int d8=0; d8<8; ++d8){
        #pragma unroll
        for (int r=0;r<4;r++)
          Opart[(size_t)slot*8192 + (w*16 + lrow + r)*128 + d8*16 + (lane&15)] = f2bf(oa[d8][r]);
      }
    }
  }
}

__global__ __launch_bounds__(256) void k_attn2_combine(
    const float* __restrict__ lp2,
    const unsigned short* __restrict__ Opart, const float* __restrict__ sv,
    float* __restrict__ ctx)
{
  __shared__ float lst[64];
  const int qt = 8 + blockIdx.x, h = blockIdx.y;
  const int nc = (qt + 8) >> 3;
  const int basel = h*72 + aoff(qt);
  const int baseo = h*48 + aoff2(qt);
  const int tid = threadIdx.x;
  if (tid < 64){
    float l = 0.f;
    for (int i=0;i<nc;i++) l += lp2[(basel+i)*64 + tid];
    lst[tid] = 1.f/l;
  }
  __syncthreads();
  #pragma unroll
  for (int e=0;e<32;e++){
    const int idx = e*256 + tid;
    const int row = idx>>7, d = idx&127;
    float a = ctx[(size_t)(qt*64+row)*EE + h*DD + d];
    for (int i=0;i<nc-1;i++)
      a += bf2f(Opart[(size_t)(baseo+i)*8192 + idx]);
    ctx[(size_t)(qt*64+row)*EE + h*DD + d] = a * sv[h*DD + d] * lst[row];
  }
}

// ---------------- host launch ----------------
extern "C" void kernel_launch(void* const* d_in, const int* in_sizes, int n_in,
                              void* d_out, int out_size, void* d_ws, size_t ws_size,
                              hipStream_t stream)
{
  (void)in_sizes; (void)n_in; (void)out_size; (void)ws_size;
  const float* hs  = (const float*)d_in[0];
  const float* q_w = (const float*)d_in[2];
  const float* q_b = (const float*)d_in[3];
  const float* k_w = (const float*)d_in[4];
  const float* k_b = (const float*)d_in[5];
  const float* v_w = (const float*)d_in[6];
  const float* v_b = (const float*)d_in[7];
  const float* o_w = (const float*)d_in[8];
  const float* o_b = (const float*)d_in[9];

  char* ws = (char*)d_ws;
  const size_t MB = 1ull<<20;
  char*           qx   = (char*)(ws + 0*MB);              // 4 MB int8; reused: qctx
  char*           qw4  = (char*)(ws + 4*MB);              // 16 MB: q,k,v,o int8 weights
  unsigned short* q_hi = (unsigned short*)(ws + 20*MB);   // 8 MB
  unsigned short* q_lo = (unsigned short*)(ws + 28*MB);   // 8 MB
  float*          kbuf = (float*)(ws + 36*MB);            // 16 MB; reused: ctx
  unsigned short* k_hi = (unsigned short*)(ws + 52*MB);   // 8 MB; reused: qkm
  float*          vbuf = (float*)(ws + 68*MB);            // 16 MB; dead after vq_transpose
  unsigned short* qvT  = (unsigned short*)(ws + 84*MB);   // 8 MB
  char*           sm   = ws + 92*MB;
  float*    sx   = (float*)(sm + 0);
  float*    sw   = (float*)(sm + 8*1024);     // 4 x 2048
  float*    sdq  = (float*)(sm + 40*1024);
  float*    il1  = (float*)(sm + 48*1024);    // 128 KB
  int*      imp  = (int*)(sm + 176*1024);
  float*    skv  = (float*)(sm + 184*1024);
  unsigned* sv_bits = (unsigned*)(sm + 192*1024);
  float*    sv   = (float*)(sm + 200*1024);
  float*    sctx = (float*)(sm + 208*1024);
  float*    nbv  = (float*)(sm + 216*1024);   // [0]=qnorm(l2e), [1]=knorm, [2]=kmix norm
  float*    qn_row = (float*)(sm + 224*1024);
  float*    kn_row = (float*)(sm + 232*1024);
  float*    kmn_row= (float*)(sm + 240*1024);
  // overlays (disjoint lifetimes, stream-ordered):
  float* lp  = (float*)qx;                       // attn1 stats partials, qx dead after QKV
  float* acc16 = (float*)qw4;                    // 128 KB in dead q_w slot
  float* partial = (float*)vbuf;                 // 4 MB  [attn1_acc .. accsum]
  unsigned short* Opart = (unsigned short*)vbuf; // 12.6 MB [attn2 .. combine]
  float* lp2 = (float*)(ws + 81*MB);             // 294 KB (in dead vbuf tail)
  unsigned short* qkm  = k_hi;
  float*          ctx  = kbuf;
  char*           qctx = qx;

  dim3 b256(256);
  dim3 ga(80, HH);

  // 1. all 5 row quantizations (hs + 4 weights) + sv_bits zeroing, one launch
  k_quant5<<<5*TT, b256, 0, stream>>>(hs, q_w, k_w, v_w, o_w, qx, qw4, sx, sw, sv_bits);
  // 2. Q/K/V projections fused (int8 MFMA, exact; Q in log2 domain), 128x128/BK=128
  k_gemm8_qkv<<<dim3(EE/128, TT/128, 3), b256, 0, stream>>>(
      qx, sx, qw4, sw, q_b, k_b, v_b, kbuf, vbuf, q_hi, q_lo, k_hi);
  // 2b. fused norms: q slice-norm, k slice-norm, v row dq-scale
  k_norm3<<<3*TT, b256, 0, stream>>>(q_hi, q_lo, kbuf, vbuf, qn_row, kn_row, sdq);
  k_redmax2<<<2, b256, 0, stream>>>(qn_row, kn_row, nbv);
  // 3. V per-column quant (row dq applied on the fly)
  k_colmax<<<dim3(EE/256, TT/64), b256, 0, stream>>>(vbuf, sdq, sv_bits);
  k_vq_transpose<<<dim3(TT/64, EE/64), b256, 0, stream>>>(vbuf, sdq, sv_bits, sv, qvT);
  // 4. attention pass 1 (swapped-operand stats; diag-branch; exp2)
  k_attn1_stats<<<ga, b256, 0, stream>>>(q_hi, q_lo, k_hi, nbv, lp);
  k_stats_combine<<<dim3(32,16), dim3(64), 0, stream>>>(lp, il1);
  k_attn1_acc<<<ga, b256, 0, stream>>>(q_hi, q_lo, k_hi, nbv, il1, partial);
  // 5. reduce + rank-count top-k per quarter
  k_accsum<<<dim3(TT/256, HH), b256, 0, stream>>>(partial, acc16);
  k_select<<<4, dim3(512), 0, stream>>>(acc16, imp);
  // 6. mixed K quantization (+ per-row dequant slice norm)
  k_quant_kmixed<<<TT, b256, 0, stream>>>(kbuf, imp, qkm, skv, kmn_row);
  k_redmax2<<<1, b256, 0, stream>>>(kmn_row, kmn_row, nbv + 2);
  // 7. attention pass 2 (dbuf, ones-MFMA l, diag-branch, exp2) + combine
  k_attn2<<<ga, b256, 0, stream>>>(q_hi, q_lo, qkm, skv, qvT, sv, nbv, ctx, lp2, Opart);
  k_attn2_combine<<<dim3(24,16), b256, 0, stream>>>(lp2, Opart, sv, ctx);
  // 8. output projection (int8 MFMA, 128x128/BK=128)
  k_rowquant8<<<TT, b256, 0, stream>>>(ctx, qctx, sctx);
  k_gemm8_one<<<dim3(EE/128, TT/128), b256, 0, stream>>>(
      qctx, sctx, qw4 + (size_t)3*EE*EE, sw + 3*EE, o_b, (float*)d_out);
}

// Round 18
// 280.609 us; speedup vs baseline: 1.0561x; 1.0561x over previous
//
#include <hip/hip_runtime.h>
#include <stdint.h>

#define TT 2048
#define EE 2048
#define HH 16
#define DD 128

static constexpr float F_EPS = 1e-5f;
// 128^-0.5 * log2(e): Q pre-scaled into log2 domain so softmax exp is a bare v_exp_f32
static constexpr float F_SCAL_L2E = (float)(0.08838834764831845 * 1.4426950408889634);

using f32x4  = __attribute__((ext_vector_type(4))) float;
using bf16x8 = __attribute__((ext_vector_type(8))) short;
using u16x8  = __attribute__((ext_vector_type(8))) unsigned short;
using i32x4  = __attribute__((ext_vector_type(4))) int;

#define MFMA_BF16(a,b,c) __builtin_amdgcn_mfma_f32_16x16x32_bf16((a),(b),(c),0,0,0)
#define MFMA_I8(a,b,c)   __builtin_amdgcn_mfma_i32_16x16x64_i8((a),(b),(c),0,0,0)

#define GLD16(gp, lp) __builtin_amdgcn_global_load_lds( \
    (__attribute__((address_space(1))) void*)(unsigned long long)(gp), \
    (__attribute__((address_space(3))) void*)(lp), 16, 0, 0)

__device__ __forceinline__ unsigned short f2bf(float x){
  unsigned u = __float_as_uint(x);
  u = (u + 0x7FFFu + ((u >> 16) & 1u)) >> 16;
  return (unsigned short)u;
}
__device__ __forceinline__ float bf2f(unsigned short h){
  return __uint_as_float(((unsigned)h) << 16);
}
// bare HW exp2 (v_exp_f32: D = 2^S0); args are in log2 domain already
__device__ __forceinline__ float exp2_hw(float x){
  float r;
  asm("v_exp_f32 %0, %1" : "=v"(r) : "v"(x));
  return r;
}
// full-block max reduce (leading sync makes it reusable)
__device__ __forceinline__ float blockmax(float am, float* red, int tid){
  __syncthreads();
  #pragma unroll
  for (int o=1;o<64;o<<=1) am = fmaxf(am, __shfl_xor(am, o));
  if ((tid&63)==0) red[tid>>6] = am;
  __syncthreads();
  return fmaxf(fmaxf(red[0],red[1]), fmaxf(red[2],red[3]));
}

// chunk enumeration: per head, 80 blocks cover the causal triangle with <=8 tiles each
__device__ __forceinline__ void cid_map(int cid, int& qt, int& ch, int& nc){
  if (cid < 8)       { qt = cid;                ch = 0;            nc = 1; }
  else if (cid < 24) { qt = 8  + ((cid-8)>>1);  ch = (cid-8)&1;    nc = 2; }
  else if (cid < 48) { qt = 16 + (cid-24)/3;    ch = (cid-24)%3;   nc = 3; }
  else               { qt = 24 + ((cid-48)>>2); ch = (cid-48)&3;   nc = 4; }
}
__device__ __forceinline__ int aoff(int qt){   // lp2 slot offset (all chunks)
  return (qt<16) ? 2*(qt-8) : ((qt<24) ? 16+3*(qt-16) : 40+4*(qt-24));
}
__device__ __forceinline__ int aoff2(int qt){  // Opart slot offset (ch>=1 only)
  return (qt<16) ? (qt-8) : ((qt<24) ? 8+2*(qt-16) : 24+3*(qt-24));
}
// XCD head-affinity remap: all blocks of one head share flat%8 => same XCD slot
__device__ __forceinline__ void attn_remap(int& h, int& cid){
  const int flat = blockIdx.y*80 + blockIdx.x;
  const int j = flat & 15;
  h = (j & 7)*2 + (j >> 3);
  cid = flat >> 4;
}

// ---- LDS staging with XOR swizzle (byte ^= (row&7)<<4) on global src + reads (bf16)
__device__ __forceinline__ void stage_k64x128(const unsigned short* gbase, unsigned short* lds, int tid){
  const char* gb = (const char*)gbase;
  char* lb = (char*)lds;
  #pragma unroll
  for (int i=0;i<4;i++){
    const int idx = i*256 + tid;
    const int r = idx >> 4, c = idx & 15;
    GLD16(gb + (size_t)r*(EE*2) + (unsigned)((c*16) ^ ((r&7)<<4)), lb + idx*16);
  }
}
__device__ __forceinline__ void stage_v128x64(const unsigned short* gbase, unsigned short* lds, int tid){
  const char* gb = (const char*)gbase;
  char* lb = (char*)lds;
  #pragma unroll
  for (int i=0;i<4;i++){
    const int idx = i*256 + tid;
    const int r = idx >> 3, c = idx & 7;
    GLD16(gb + (size_t)r*(TT*2) + (unsigned)((c*16) ^ ((r&7)<<4)), lb + idx*16);
  }
}
__device__ __forceinline__ bf16x8 frag_k(const unsigned short* lds, int kr, int dbyte){
  return *(const bf16x8*)((const char*)lds + kr*256 + (dbyte ^ ((kr&7)<<4)));
}
__device__ __forceinline__ bf16x8 frag_v(const unsigned short* lds, int dr, int kbyte){
  return *(const bf16x8*)((const char*)lds + dr*128 + (kbyte ^ ((dr&7)<<4)));
}

// ------- fused row quantization: hs + 4 weights -> int8 (+ sv_bits zeroing) --------
__global__ __launch_bounds__(256) void k_quant5(
    const float* __restrict__ hs, const float* __restrict__ qwf,
    const float* __restrict__ kwf, const float* __restrict__ vwf,
    const float* __restrict__ owf,
    char* __restrict__ qx, char* __restrict__ qw4,
    float* __restrict__ sx, float* __restrict__ sw,
    unsigned* __restrict__ sv_bits)
{
  __shared__ float red[4];
  const int which = blockIdx.x >> 11;
  const int row = blockIdx.x & (TT-1);
  const int tid = threadIdx.x;
  if (blockIdx.x < 8) sv_bits[blockIdx.x*256 + tid] = 0u;   // zero before k_colmax
  const float* in; char* outq; float* outs;
  if      (which==0){ in=hs;  outq=qx;                   outs=sx;      }
  else if (which==1){ in=qwf; outq=qw4;                  outs=sw;      }
  else if (which==2){ in=kwf; outq=qw4+(size_t)EE*EE;    outs=sw+EE;   }
  else if (which==3){ in=vwf; outq=qw4+(size_t)2*EE*EE;  outs=sw+2*EE; }
  else              { in=owf; outq=qw4+(size_t)3*EE*EE;  outs=sw+3*EE; }
  const float* r = in + (size_t)row * EE;
  float x[8];
  {
    const f32x4 a = *(const f32x4*)(r + tid*8);
    const f32x4 b = *(const f32x4*)(r + tid*8 + 4);
    x[0]=a[0]; x[1]=a[1]; x[2]=a[2]; x[3]=a[3];
    x[4]=b[0]; x[5]=b[1]; x[6]=b[2]; x[7]=b[3];
  }
  float am = 0.f;
  #pragma unroll
  for (int j=0;j<8;j++) am = fmaxf(am, fabsf(x[j]));
  am = blockmax(am, red, tid);
  const float s = fmaxf(am, F_EPS) / 127.f;
  if (tid==0) outs[row] = s;
  union { char c[8]; int2 v; } u;
  #pragma unroll
  for (int j=0;j<8;j++) u.c[j] = (char)(int)rintf(x[j]/s);
  *(int2*)(outq + (size_t)row*EE + tid*8) = u.v;
}

// generic single-array int8 row quant (for ctx)
__global__ __launch_bounds__(256) void k_rowquant8(
    const float* __restrict__ in, char* __restrict__ outq, float* __restrict__ outs)
{
  __shared__ float red[4];
  const int row = blockIdx.x;
  const int tid = threadIdx.x;
  const float* r = in + (size_t)row * EE;
  float x[8];
  {
    const f32x4 a = *(const f32x4*)(r + tid*8);
    const f32x4 b = *(const f32x4*)(r + tid*8 + 4);
    x[0]=a[0]; x[1]=a[1]; x[2]=a[2]; x[3]=a[3];
    x[4]=b[0]; x[5]=b[1]; x[6]=b[2]; x[7]=b[3];
  }
  float am = 0.f;
  #pragma unroll
  for (int j=0;j<8;j++) am = fmaxf(am, fabsf(x[j]));
  am = blockmax(am, red, tid);
  const float s = fmaxf(am, F_EPS) / 127.f;
  if (tid==0) outs[row] = s;
  union { char c[8]; int2 v; } u;
  #pragma unroll
  for (int j=0;j<8;j++) u.c[j] = (char)(int)rintf(x[j]/s);
  *(int2*)(outq + (size_t)row*EE + tid*8) = u.v;
}

// mixed K quantization (bf16-int out for attn2 MFMA) + per-row dequant slice norm
__global__ __launch_bounds__(256) void k_quant_kmixed(
    const float* __restrict__ kin, const int* __restrict__ imp,
    unsigned short* __restrict__ qkm, float* __restrict__ sk,
    float* __restrict__ kmn)
{
  __shared__ float red[4];
  const int row = blockIdx.x;
  const int tid = threadIdx.x;
  const float* r = kin + (size_t)row * EE;
  float x[8];
  {
    const f32x4 a = *(const f32x4*)(r + tid*8);
    const f32x4 b = *(const f32x4*)(r + tid*8 + 4);
    x[0]=a[0]; x[1]=a[1]; x[2]=a[2]; x[3]=a[3];
    x[4]=b[0]; x[5]=b[1]; x[6]=b[2]; x[7]=b[3];
  }
  float am = 0.f;
  #pragma unroll
  for (int j=0;j<8;j++) am = fmaxf(am, fabsf(x[j]));
  am = blockmax(am, red, tid);
  float s;
  if (imp[row]) s = fmaxf(am / 127.f, F_EPS);
  else          s = fmaxf(am, F_EPS) / 7.f;
  if (tid==0) sk[row] = s;
  u16x8 qv;
  float ss = 0.f;
  #pragma unroll
  for (int j=0;j<8;j++){
    const float p = rintf(x[j]/s);
    qv[j] = f2bf(p);
    const float dq = p*s;
    ss += dq*dq;
  }
  *(u16x8*)(qkm + (size_t)row*EE + tid*8) = qv;
  ss += __shfl_xor(ss,1); ss += __shfl_xor(ss,2);
  ss += __shfl_xor(ss,4); ss += __shfl_xor(ss,8);
  const float mx = blockmax(ss, red, tid);
  if (tid==0) kmn[row] = __builtin_sqrtf(mx);
}

// ---- fused norms: q hi/lo slice norm, k slice norm, v row dq-scale ----
__global__ __launch_bounds__(256) void k_norm3(
    const unsigned short* __restrict__ qhi, const unsigned short* __restrict__ qlo,
    const float* __restrict__ kbuf, const float* __restrict__ vbuf,
    float* __restrict__ qn, float* __restrict__ kn, float* __restrict__ sdq)
{
  __shared__ float red[4];
  const int which = blockIdx.x >> 11;
  const int row = blockIdx.x & (TT-1);
  const int tid = threadIdx.x;
  if (which == 0){
    const u16x8 h = *(const u16x8*)(qhi + (size_t)row*EE + tid*8);
    const u16x8 l = *(const u16x8*)(qlo + (size_t)row*EE + tid*8);
    float ss = 0.f;
    #pragma unroll
    for (int j=0;j<8;j++){
      const float v = bf2f(h[j]) + bf2f(l[j]);
      ss += v*v;
    }
    ss += __shfl_xor(ss,1); ss += __shfl_xor(ss,2);
    ss += __shfl_xor(ss,4); ss += __shfl_xor(ss,8);
    const float mx = blockmax(ss, red, tid);
    if (tid==0) qn[row] = __builtin_sqrtf(mx);
  } else if (which == 1){
    const f32x4 a = *(const f32x4*)(kbuf + (size_t)row*EE + tid*8);
    const f32x4 b = *(const f32x4*)(kbuf + (size_t)row*EE + tid*8 + 4);
    float ss = a[0]*a[0]+a[1]*a[1]+a[2]*a[2]+a[3]*a[3]
             + b[0]*b[0]+b[1]*b[1]+b[2]*b[2]+b[3]*b[3];
    ss += __shfl_xor(ss,1); ss += __shfl_xor(ss,2);
    ss += __shfl_xor(ss,4); ss += __shfl_xor(ss,8);
    const float mx = blockmax(ss, red, tid);
    if (tid==0) kn[row] = __builtin_sqrtf(mx);
  } else {
    const f32x4 a = *(const f32x4*)(vbuf + (size_t)row*EE + tid*8);
    const f32x4 b = *(const f32x4*)(vbuf + (size_t)row*EE + tid*8 + 4);
    float am = fmaxf(fmaxf(fmaxf(fabsf(a[0]),fabsf(a[1])), fmaxf(fabsf(a[2]),fabsf(a[3]))),
                     fmaxf(fmaxf(fabsf(b[0]),fabsf(b[1])), fmaxf(fabsf(b[2]),fabsf(b[3]))));
    am = blockmax(am, red, tid);
    if (tid==0) sdq[row] = fmaxf(am, F_EPS) / 127.f;
  }
}

__global__ __launch_bounds__(256) void k_redmax2(
    const float* __restrict__ a, const float* __restrict__ b, float* __restrict__ dst)
{
  const float* s = blockIdx.x ? b : a;
  const int tid = threadIdx.x;
  float m = 0.f;
  #pragma unroll
  for (int i=0;i<8;i++) m = fmaxf(m, s[tid + i*256]);
  #pragma unroll
  for (int o=1;o<64;o<<=1) m = fmaxf(m, __shfl_xor(m,o));
  __shared__ float red[4];
  if ((tid&63)==0) red[tid>>6]=m;
  __syncthreads();
  if (tid==0) dst[blockIdx.x] = fmaxf(fmaxf(red[0],red[1]), fmaxf(red[2],red[3]));
}

// ---------------- int8 GEMM core: 128x128 tile, BK=64, exact i32 dot ----------------
// LDS swizzle: byte ^= ((row>>1)&3)<<4 (2-way bank alias = free)
__device__ __forceinline__ void gemm8_body(
    const char* __restrict__ Aq, const float* __restrict__ sa,
    const char* __restrict__ Bq, const float* __restrict__ sb,
    const float* __restrict__ bias, float post,
    float* __restrict__ Cout, unsigned short* __restrict__ Hout,
    unsigned short* __restrict__ Lout,
    char* lA, char* lB)
{
  const int tid = threadIdx.x;
  const int bm = blockIdx.y, bn = blockIdx.x;
  const int lane = tid & 63, w = tid >> 6;
  const int wr = w >> 1, wc = w & 1;           // wave grid 2x2, each 64x64 output
  i32x4 acc[4][4];
  const i32x4 IZ = {0,0,0,0};
  #pragma unroll
  for (int i=0;i<4;i++)
    #pragma unroll
    for (int j=0;j<4;j++) acc[i][j] = IZ;

  const char* gA = Aq + (size_t)(bm*128)*EE;
  const char* gB = Bq + (size_t)(bn*128)*EE;

  for (int k0 = 0; k0 < EE; k0 += 64) {
    #pragma unroll
    for (int i=0;i<2;i++){
      const int c = i*256 + tid;               // A: 512 chunks (128 rows x 4)
      const int rr = c >> 2, k16 = c & 3;
      GLD16(gA + (size_t)rr*EE + k0 + ((k16*16) ^ (((rr>>1)&3)<<4)), lA + c*16);
    }
    #pragma unroll
    for (int i=0;i<2;i++){
      const int c = i*256 + tid;               // B: 512 chunks (128 rows x 4)
      const int rr = c >> 2, k16 = c & 3;
      GLD16(gB + (size_t)rr*EE + k0 + ((k16*16) ^ (((rr>>1)&3)<<4)), lB + c*16);
    }
    __syncthreads();
    i32x4 af[4], bf[4];
    #pragma unroll
    for (int mi=0;mi<4;mi++){
      const int rr = wr*64 + mi*16 + (lane&15);
      af[mi] = *(const i32x4*)(lA + rr*64 + (((lane>>4)*16) ^ (((rr>>1)&3)<<4)));
    }
    #pragma unroll
    for (int ni=0;ni<4;ni++){
      const int rr = wc*64 + ni*16 + (lane&15);
      bf[ni] = *(const i32x4*)(lB + rr*64 + (((lane>>4)*16) ^ (((rr>>1)&3)<<4)));
    }
    #pragma unroll
    for (int mi=0;mi<4;mi++)
      #pragma unroll
      for (int ni=0;ni<4;ni++)
        acc[mi][ni] = MFMA_I8(af[mi], bf[ni], acc[mi][ni]);
    __syncthreads();
  }
  const int row0 = bm*128 + wr*64;
  const int col0 = bn*128 + wc*64;
  #pragma unroll
  for (int mi=0;mi<4;mi++){
    #pragma unroll
    for (int r=0;r<4;r++){
      const int row = row0 + mi*16 + (lane>>4)*4 + r;
      const float sav = sa[row];
      #pragma unroll
      for (int ni=0;ni<4;ni++){
        const int col = col0 + ni*16 + (lane&15);
        const float v = ((float)acc[mi][ni][r]*sav*sb[col] + bias[col]) * post;
        if (Cout) Cout[(size_t)row*EE + col] = v;
        if (Hout){
          const unsigned short hh = f2bf(v);
          Hout[(size_t)row*EE + col] = hh;
          if (Lout) Lout[(size_t)row*EE + col] = f2bf(v - bf2f(hh));
        }
      }
    }
  }
}

__global__ __launch_bounds__(256) void k_gemm8_qkv(
    const char* __restrict__ Aq, const float* __restrict__ sa,
    const char* __restrict__ qw4, const float* __restrict__ sw,
    const float* __restrict__ q_b, const float* __restrict__ k_b,
    const float* __restrict__ v_b,
    float* __restrict__ kbuf, float* __restrict__ vbuf,
    unsigned short* __restrict__ q_hi, unsigned short* __restrict__ q_lo,
    unsigned short* __restrict__ k_hi)
{
  __shared__ char lA[128*64];
  __shared__ char lB[128*64];
  const int z = blockIdx.z;
  const char* Bq = qw4 + (size_t)z*EE*EE;
  const float* sb = sw + z*EE;
  const float* bias = (z==0) ? q_b : (z==1) ? k_b : v_b;
  const float post = (z==0) ? F_SCAL_L2E : 1.f;   // Q carries scaling*log2(e)
  float* Cout = (z==1) ? kbuf : (z==2) ? vbuf : nullptr;
  unsigned short* Hout = (z==0) ? q_hi : (z==1) ? k_hi : nullptr;
  unsigned short* Lout = (z==0) ? q_lo : nullptr;
  gemm8_body(Aq, sa, Bq, sb, bias, post, Cout, Hout, Lout, lA, lB);
}

__global__ __launch_bounds__(256) void k_gemm8_one(
    const char* __restrict__ Aq, const float* __restrict__ sa,
    const char* __restrict__ Bq, const float* __restrict__ sb,
    const float* __restrict__ bias, float* __restrict__ Cout)
{
  __shared__ char lA[128*64];
  __shared__ char lB[128*64];
  gemm8_body(Aq, sa, Bq, sb, bias, 1.f, Cout, nullptr, nullptr, lA, lB);
}

// ---------------- V per-column quant (dq on the fly) ----------------
__global__ __launch_bounds__(256) void k_colmax(
    const float* __restrict__ v, const float* __restrict__ sdq,
    unsigned* __restrict__ sv_bits)
{
  const int e = blockIdx.x*256 + threadIdx.x;
  const int t0 = blockIdx.y*64;
  float am = 0.f;
  for (int t=t0; t<t0+64; ++t){
    const float s = sdq[t];
    const float dq = rintf(v[(size_t)t*EE + e]/s)*s;
    am = fmaxf(am, fabsf(dq));
  }
  atomicMax(sv_bits + e, __float_as_uint(am));
}

__global__ __launch_bounds__(256) void k_vq_transpose(
    const float* __restrict__ v, const float* __restrict__ sdq,
    const unsigned* __restrict__ sv_bits,
    float* __restrict__ sv, unsigned short* __restrict__ qvT)
{
  __shared__ unsigned short tile[64][66];
  const int t0 = blockIdx.x*64, e0 = blockIdx.y*64;
  const int tid = threadIdx.x;
  {
    const int ee = tid & 63, tb = (tid>>6)*16;
    const float sve = fmaxf(__uint_as_float(sv_bits[e0+ee]), F_EPS) / 127.f;
    for (int i=0;i<16;i++){
      const int t = t0+tb+i;
      const float s = sdq[t];
      const float dq = rintf(v[(size_t)t*EE + e0+ee]/s)*s;
      tile[tb+i][ee] = f2bf(rintf(dq / sve));
    }
  }
  if (blockIdx.x==0 && tid<64)
    sv[e0+tid] = fmaxf(__uint_as_float(sv_bits[e0+tid]), F_EPS) / 127.f;
  __syncthreads();
  {
    const int ttl = tid & 63, ebl = (tid>>6)*16;
    for (int i=0;i<16;i++)
      qvT[(size_t)(e0+ebl+i)*TT + t0+ttl] = tile[ttl][ebl+i];
  }
}

// ---- attention pass 1: chunked denominators (swapped QK^T: S[key][query]) ---------
__global__ __launch_bounds__(256) void k_attn1_stats(
    const unsigned short* __restrict__ qh, const unsigned short* __restrict__ ql,
    const unsigned short* __restrict__ kh,
    const float* __restrict__ nbv, float* __restrict__ lp)
{
  __shared__ unsigned short lKh[64*128];
  int h, cid; attn_remap(h, cid);
  int qt, ch, nc; cid_map(cid, qt, ch, nc);
  const int per = (qt + nc)/nc;
  const int s0 = ch*per, s1 = min(s0+per-1, qt);
  const int tid = threadIdx.x, w = tid>>6, lane = tid&63;
  const int row_base = qt*64 + w*16, lrow = (lane>>4)*4;
  const float B1 = nbv[0] * nbv[1] * 1.001f + 1e-3f;
  bf16x8 qhf[4], qlf[4];
  {
    const size_t qo = (size_t)(row_base + (lane&15))*EE + h*DD + (lane>>4)*8;
    #pragma unroll
    for (int kc=0;kc<4;kc++){
      qhf[kc] = *(const bf16x8*)(qh + qo + kc*32);
      qlf[kc] = *(const bf16x8*)(ql + qo + kc*32);
    }
  }
  const int query = row_base + (lane&15);
  float l_acc = 0.f;
  stage_k64x128(kh + (size_t)(s0*64)*EE + h*DD, lKh, tid);
  for (int st=s0; st<=s1; ++st){
    __syncthreads();
    f32x4 S[4];
    #pragma unroll
    for (int n=0;n<4;n++){
      f32x4 a = {0.f,0.f,0.f,0.f};
      const int kr = n*16 + (lane&15);
      #pragma unroll
      for (int kc=0;kc<4;kc++){
        const int db = kc*64 + (lane>>4)*16;
        const bf16x8 khf = frag_k(lKh, kr, db);
        a = MFMA_BF16(khf, qhf[kc], a);
        a = MFMA_BF16(khf, qlf[kc], a);
      }
      S[n] = a;
    }
    __syncthreads();
    if (st < s1)
      stage_k64x128(kh + (size_t)((st+1)*64)*EE + h*DD, lKh, tid);
    float ls = 0.f;
    if (st == qt){                       // diagonal tile: causal masking needed
      #pragma unroll
      for (int n=0;n<4;n++){
        #pragma unroll
        for (int r=0;r<4;r++){
          const int key = st*64 + n*16 + lrow + r;
          ls += (key<=query) ? exp2_hw(S[n][r]-B1) : 0.f;
        }
      }
    } else {                             // fully below diagonal: all keys valid
      #pragma unroll
      for (int n=0;n<4;n++){
        #pragma unroll
        for (int r=0;r<4;r++)
          ls += exp2_hw(S[n][r]-B1);
      }
    }
    ls += __shfl_xor(ls,16);
    ls += __shfl_xor(ls,32);
    l_acc += ls;
  }
  if (lane < 16){
    const int slot = (h*80 + cid)*64;
    lp[slot + w*16 + lane] = l_acc;
  }
}

__global__ __launch_bounds__(64) void k_stats_combine(
    const float* __restrict__ lp, float* __restrict__ il1)
{
  const int qt = blockIdx.x, h = blockIdx.y, r = threadIdx.x;
  const int nc  = (qt<8)?1:((qt<16)?2:((qt<24)?3:4));
  const int off = (qt<8)?qt:((qt<16)?8+2*(qt-8):((qt<24)?24+3*(qt-16):48+4*(qt-24)));
  const int base = (h*80 + off)*64 + r;
  float l = 0.f;
  for (int i=0;i<nc;i++) l += lp[base + i*64];
  il1[h*TT + qt*64 + r] = 1.f/l;
}

// ---------------- attention pass 1b: column sums (2-MFMA, K-hi only) ---------------
__global__ __launch_bounds__(256) void k_attn1_acc(
    const unsigned short* __restrict__ qh, const unsigned short* __restrict__ ql,
    const unsigned short* __restrict__ kh,
    const float* __restrict__ nbv, const float* __restrict__ il1,
    float* __restrict__ partial)
{
  __shared__ unsigned short lKh[64*128];
  __shared__ float accw[4][512];
  int h, cid; attn_remap(h, cid);
  int qt, ch, nc; cid_map(cid, qt, ch, nc);
  const int per = (qt + nc)/nc;
  const int s0 = ch*per, s1 = min(s0+per-1, qt);
  const int tid = threadIdx.x, w = tid>>6, lane = tid&63;
  const int row_base = qt*64 + w*16, lrow = (lane>>4)*4;
  const float B1 = nbv[0] * nbv[1] * 1.001f + 1e-3f;
  bf16x8 qhf[4], qlf[4];
  {
    const size_t qo = (size_t)(row_base + (lane&15))*EE + h*DD + (lane>>4)*8;
    #pragma unroll
    for (int kc=0;kc<4;kc++){
      qhf[kc] = *(const bf16x8*)(qh + qo + kc*32);
      qlf[kc] = *(const bf16x8*)(ql + qo + kc*32);
    }
  }
  float il_r[4];
  #pragma unroll
  for (int r=0;r<4;r++)
    il_r[r] = il1[h*TT + row_base + lrow + r];
  stage_k64x128(kh + (size_t)(s0*64)*EE + h*DD, lKh, tid);
  for (int st=s0; st<=s1; ++st){
    __syncthreads();
    f32x4 S[4];
    #pragma unroll
    for (int n=0;n<4;n++){
      f32x4 a = {0.f,0.f,0.f,0.f};
      const int kr = n*16 + (lane&15);
      #pragma unroll
      for (int kc=0;kc<4;kc++){
        const int db = kc*64 + (lane>>4)*16;
        const bf16x8 khf = frag_k(lKh, kr, db);
        a = MFMA_BF16(qhf[kc], khf, a);
        a = MFMA_BF16(qlf[kc], khf, a);
      }
      S[n] = a;
    }
    __syncthreads();
    if (st < s1)
      stage_k64x128(kh + (size_t)((st+1)*64)*EE + h*DD, lKh, tid);
    if (st == qt){                       // diagonal tile: causal masking needed
      #pragma unroll
      for (int n=0;n<4;n++){
        const int col = st*64 + n*16 + (lane&15);
        float cs = 0.f;
        #pragma unroll
        for (int r=0;r<4;r++){
          const int row = row_base + lrow + r;
          cs += (col<=row) ? exp2_hw(S[n][r]-B1)*il_r[r] : 0.f;
        }
        cs += __shfl_xor(cs,16);
        cs += __shfl_xor(cs,32);
        if (lane < 16) accw[w][(st-s0)*64 + n*16 + lane] = cs;
      }
    } else {
      #pragma unroll
      for (int n=0;n<4;n++){
        float cs = 0.f;
        #pragma unroll
        for (int r=0;r<4;r++)
          cs += exp2_hw(S[n][r]-B1)*il_r[r];
        cs += __shfl_xor(cs,16);
        cs += __shfl_xor(cs,32);
        if (lane < 16) accw[w][(st-s0)*64 + n*16 + lane] = cs;
      }
    }
  }
  __syncthreads();
  const int ncols = (s1-s0+1)*64;
  float* dst = partial + (size_t)(h*32+qt)*TT + s0*64;
  for (int i=tid; i<ncols; i+=256)
    dst[i] = accw[0][i]+accw[1][i]+accw[2][i]+accw[3][i];
}

// ---------------- acc reduce + rank-count top-51 selection ----------------
__global__ __launch_bounds__(256) void k_accsum(
    const float* __restrict__ partial, float* __restrict__ acc16)
{
  const int s = blockIdx.x*256 + threadIdx.x;
  const int hh = blockIdx.y;
  const int tmin = s >> 6;
  float a = 0.f;
  for (int qt=tmin; qt<32; ++qt)
    a += partial[(size_t)(hh*32+qt)*TT + s];
  acc16[hh*TT + s] = a;
}

__global__ __launch_bounds__(512) void k_select(
    const float* __restrict__ acc16, int* __restrict__ imp)
{
  __shared__ float vals[512];
  const int tid = threadIdx.x;
  const int s = blockIdx.x*512 + tid;
  float a = 0.f;
  #pragma unroll
  for (int hh=0; hh<16; ++hh) a += acc16[hh*TT + s];
  a = a / (float)(TT - s) / 16.f;
  vals[tid] = a;
  __syncthreads();
  int rank = 0;
  for (int j=0; j<512; ++j){
    const float vj = vals[j];
    rank += (vj > a) || (vj == a && j < tid);
  }
  imp[s] = (rank < 51) ? 1 : 0;
}

// ------ attention pass 2: chunked flash, dbuf K/V, l via ones-MFMA on P ------------
__global__ __launch_bounds__(256) void k_attn2(
    const unsigned short* __restrict__ qh, const unsigned short* __restrict__ ql,
    const unsigned short* __restrict__ qkm, const float* __restrict__ sk,
    const unsigned short* __restrict__ qvT, const float* __restrict__ sv,
    const float* __restrict__ nbv,
    float* __restrict__ ctx, float* __restrict__ lp2,
    unsigned short* __restrict__ Opart)
{
  __shared__ unsigned short lKA[64*128];
  __shared__ unsigned short lVA[128*64];
  __shared__ unsigned short lKB[64*128];
  __shared__ unsigned short lVB[128*64];
  __shared__ unsigned short Ph[4][16*64];
  int h, cid; attn_remap(h, cid);
  int qt, ch, nc; cid_map(cid, qt, ch, nc);
  const int per = (qt + nc)/nc;
  const int s0 = ch*per, s1 = min(s0+per-1, qt);
  const int tid = threadIdx.x, w = tid>>6, lane = tid&63;
  const int row_base = qt*64 + w*16, lrow = (lane>>4)*4;
  const float B2 = nbv[0] * nbv[2] * 1.001f + 1e-3f;
  unsigned short *curK = lKA, *curV = lVA, *nxtK = lKB, *nxtV = lVB;
  stage_k64x128(qkm + (size_t)(s0*64)*EE + h*DD, curK, tid);
  stage_v128x64(qvT + (size_t)(h*DD)*TT + s0*64, curV, tid);
  bf16x8 qhf[4], qlf[4];
  {
    const size_t qo = (size_t)(row_base + (lane&15))*EE + h*DD + (lane>>4)*8;
    #pragma unroll
    for (int kc=0;kc<4;kc++){
      qhf[kc] = *(const bf16x8*)(qh + qo + kc*32);
      qlf[kc] = *(const bf16x8*)(ql + qo + kc*32);
    }
  }
  const short ONE = (short)0x3F80;
  const bf16x8 ONESV = {ONE,ONE,ONE,ONE,ONE,ONE,ONE,ONE};
  f32x4 lsum;
  f32x4 oa[8];
  const f32x4 FZ = {0.f,0.f,0.f,0.f};
  lsum = FZ;
  #pragma unroll
  for (int d8=0; d8<8; ++d8) oa[d8] = FZ;

  for (int st=s0; st<=s1; ++st){
    __syncthreads();                       // cur staged; drains prev prefetch
    if (st < s1){
      stage_k64x128(qkm + (size_t)((st+1)*64)*EE + h*DD, nxtK, tid);
      stage_v128x64(qvT + (size_t)(h*DD)*TT + (st+1)*64, nxtV, tid);
    }
    f32x4 S[4];
    #pragma unroll
    for (int n=0;n<4;n++){
      f32x4 a = {0.f,0.f,0.f,0.f};
      const int kr = n*16 + (lane&15);
      #pragma unroll
      for (int kc=0;kc<4;kc++){
        const int db = kc*64 + (lane>>4)*16;
        const bf16x8 kf = frag_k(curK, kr, db);
        a = MFMA_BF16(qhf[kc], kf, a);
        a = MFMA_BF16(qlf[kc], kf, a);
      }
      S[n] = a * sk[st*64 + n*16 + (lane&15)];
    }
    if (st == qt){                       // diagonal tile: causal masking needed
      #pragma unroll
      for (int r=0;r<4;r++){
        const int row = row_base + lrow + r;
        #pragma unroll
        for (int n=0;n<4;n++){
          const int col = st*64 + n*16 + (lane&15);
          const float pv = (col<=row) ? exp2_hw(S[n][r]-B2) : 0.f;
          *(unsigned short*)((char*)&Ph[w][0] + (lrow+r)*128 +
              ((((n*16 + (lane&15))*2)) ^ (((lrow+r)&7)<<4))) = f2bf(pv);
        }
      }
    } else {
      #pragma unroll
      for (int r=0;r<4;r++){
        #pragma unroll
        for (int n=0;n<4;n++){
          const float pv = exp2_hw(S[n][r]-B2);
          *(unsigned short*)((char*)&Ph[w][0] + (lrow+r)*128 +
              ((((n*16 + (lane&15))*2)) ^ (((lrow+r)&7)<<4))) = f2bf(pv);
        }
      }
    }
    // per-wave LDS write->read (in-wave lgkmcnt ordering)
    bf16x8 pah[2];
    #pragma unroll
    for (int kc=0;kc<2;kc++){
      const int rr = lane&15;
      const int cb = kc*64 + (lane>>4)*16;
      pah[kc] = *(const bf16x8*)((const char*)&Ph[w][0] + rr*128 + (cb ^ ((rr&7)<<4)));
    }
    // softmax denominator via ones-MFMA (consistent with bf16 P used in PV)
    lsum = MFMA_BF16(pah[0], ONESV, lsum);
    lsum = MFMA_BF16(pah[1], ONESV, lsum);
    #pragma unroll
    for (int d8=0; d8<8; ++d8){
      const int dr = d8*16 + (lane&15);
      const int kb = (lane>>4)*16;
      const bf16x8 v0 = frag_v(curV, dr, kb);
      const bf16x8 v1 = frag_v(curV, dr, kb + 64);
      oa[d8] = MFMA_BF16(pah[0], v0, oa[d8]);
      oa[d8] = MFMA_BF16(pah[1], v1, oa[d8]);
    }
    unsigned short* t;
    t = curK; curK = nxtK; nxtK = t;
    t = curV; curV = nxtV; nxtV = t;
  }
  if (nc == 1){
    #pragma unroll
    for (int d8=0; d8<8; ++d8){
      const float sve = sv[h*DD + d8*16 + (lane&15)];
      #pragma unroll
      for (int r=0;r<4;r++){
        const int row = row_base + lrow + r;
        ctx[(size_t)row*EE + h*DD + d8*16 + (lane&15)] = oa[d8][r]*sve/lsum[r];
      }
    }
  } else {
    const int slotl = h*72 + aoff(qt) + ch;
    if ((lane&15)==0){
      #pragma unroll
      for (int r=0;r<4;r++)
        lp2[slotl*64 + w*16 + lrow + r] = lsum[r];
    }
    if (ch == 0){
      #pragma unroll
      for (int d8=0; d8<8; ++d8){
        #pragma unroll
        for (int r=0;r<4;r++){
          const int row = row_base + lrow + r;
          ctx[(size_t)row*EE + h*DD + d8*16 + (lane&15)] = oa[d8][r];
        }
      }
    } else {
      const int slot = h*48 + aoff2(qt) + (ch-1);
      #pragma unroll
      for (int d8=0; d8<8; ++d8){
        #pragma unroll
        for (int r=0;r<4;r++)
          Opart[(size_t)slot*8192 + (w*16 + lrow + r)*128 + d8*16 + (lane&15)] = f2bf(oa[d8][r]);
      }
    }
  }
}

__global__ __launch_bounds__(256) void k_attn2_combine(
    const float* __restrict__ lp2,
    const unsigned short* __restrict__ Opart, const float* __restrict__ sv,
    float* __restrict__ ctx)
{
  __shared__ float lst[64];
  const int qt = 8 + blockIdx.x, h = blockIdx.y;
  const int nc = (qt + 8) >> 3;
  const int basel = h*72 + aoff(qt);
  const int baseo = h*48 + aoff2(qt);
  const int tid = threadIdx.x;
  if (tid < 64){
    float l = 0.f;
    for (int i=0;i<nc;i++) l += lp2[(basel+i)*64 + tid];
    lst[tid] = 1.f/l;
  }
  __syncthreads();
  #pragma unroll
  for (int e=0;e<32;e++){
    const int idx = e*256 + tid;
    const int row = idx>>7, d = idx&127;
    float a = ctx[(size_t)(qt*64+row)*EE + h*DD + d];
    for (int i=0;i<nc-1;i++)
      a += bf2f(Opart[(size_t)(baseo+i)*8192 + idx]);
    ctx[(size_t)(qt*64+row)*EE + h*DD + d] = a * sv[h*DD + d] * lst[row];
  }
}

// ---------------- host launch ----------------
extern "C" void kernel_launch(void* const* d_in, const int* in_sizes, int n_in,
                              void* d_out, int out_size, void* d_ws, size_t ws_size,
                              hipStream_t stream)
{
  (void)in_sizes; (void)n_in; (void)out_size; (void)ws_size;
  const float* hs  = (const float*)d_in[0];
  const float* q_w = (const float*)d_in[2];
  const float* q_b = (const float*)d_in[3];
  const float* k_w = (const float*)d_in[4];
  const float* k_b = (const float*)d_in[5];
  const float* v_w = (const float*)d_in[6];
  const float* v_b = (const float*)d_in[7];
  const float* o_w = (const float*)d_in[8];
  const float* o_b = (const float*)d_in[9];

  char* ws = (char*)d_ws;
  const size_t MB = 1ull<<20;
  char*           qx   = (char*)(ws + 0*MB);              // 4 MB int8; reused: qctx
  char*           qw4  = (char*)(ws + 4*MB);              // 16 MB: q,k,v,o int8 weights
  unsigned short* q_hi = (unsigned short*)(ws + 20*MB);   // 8 MB
  unsigned short* q_lo = (unsigned short*)(ws + 28*MB);   // 8 MB
  float*          kbuf = (float*)(ws + 36*MB);            // 16 MB; reused: ctx
  unsigned short* k_hi = (unsigned short*)(ws + 52*MB);   // 8 MB; reused: qkm
  float*          vbuf = (float*)(ws + 68*MB);            // 16 MB; dead after vq_transpose
  unsigned short* qvT  = (unsigned short*)(ws + 84*MB);   // 8 MB
  char*           sm   = ws + 92*MB;
  float*    sx   = (float*)(sm + 0);
  float*    sw   = (float*)(sm + 8*1024);     // 4 x 2048
  float*    sdq  = (float*)(sm + 40*1024);
  float*    il1  = (float*)(sm + 48*1024);    // 128 KB
  int*      imp  = (int*)(sm + 176*1024);
  float*    skv  = (float*)(sm + 184*1024);
  unsigned* sv_bits = (unsigned*)(sm + 192*1024);
  float*    sv   = (float*)(sm + 200*1024);
  float*    sctx = (float*)(sm + 208*1024);
  float*    nbv  = (float*)(sm + 216*1024);   // [0]=qnorm(l2e), [1]=knorm, [2]=kmix norm
  float*    qn_row = (float*)(sm + 224*1024);
  float*    kn_row = (float*)(sm + 232*1024);
  float*    kmn_row= (float*)(sm + 240*1024);
  // overlays (disjoint lifetimes, stream-ordered):
  float* lp  = (float*)qx;                       // attn1 stats partials, qx dead after QKV
  float* acc16 = (float*)qw4;                    // 128 KB in dead q_w slot
  float* partial = (float*)vbuf;                 // 4 MB  [attn1_acc .. accsum]
  unsigned short* Opart = (unsigned short*)vbuf; // 12.6 MB [attn2 .. combine]
  float* lp2 = (float*)(ws + 81*MB);             // 294 KB (in dead vbuf tail)
  unsigned short* qkm  = k_hi;
  float*          ctx  = kbuf;
  char*           qctx = qx;

  dim3 b256(256);
  dim3 ga(80, HH);

  // 1. all 5 row quantizations (hs + 4 weights) + sv_bits zeroing, one launch
  k_quant5<<<5*TT, b256, 0, stream>>>(hs, q_w, k_w, v_w, o_w, qx, qw4, sx, sw, sv_bits);
  // 2. Q/K/V projections fused (int8 MFMA, exact; Q in log2 domain), 128x128/BK=64
  k_gemm8_qkv<<<dim3(EE/128, TT/128, 3), b256, 0, stream>>>(
      qx, sx, qw4, sw, q_b, k_b, v_b, kbuf, vbuf, q_hi, q_lo, k_hi);
  // 2b. fused norms: q slice-norm, k slice-norm, v row dq-scale
  k_norm3<<<3*TT, b256, 0, stream>>>(q_hi, q_lo, kbuf, vbuf, qn_row, kn_row, sdq);
  k_redmax2<<<2, b256, 0, stream>>>(qn_row, kn_row, nbv);
  // 3. V per-column quant (row dq applied on the fly)
  k_colmax<<<dim3(EE/256, TT/64), b256, 0, stream>>>(vbuf, sdq, sv_bits);
  k_vq_transpose<<<dim3(TT/64, EE/64), b256, 0, stream>>>(vbuf, sdq, sv_bits, sv, qvT);
  // 4. attention pass 1 (swapped-operand stats; diag-branch; exp2)
  k_attn1_stats<<<ga, b256, 0, stream>>>(q_hi, q_lo, k_hi, nbv, lp);
  k_stats_combine<<<dim3(32,16), dim3(64), 0, stream>>>(lp, il1);
  k_attn1_acc<<<ga, b256, 0, stream>>>(q_hi, q_lo, k_hi, nbv, il1, partial);
  // 5. reduce + rank-count top-k per quarter
  k_accsum<<<dim3(TT/256, HH), b256, 0, stream>>>(partial, acc16);
  k_select<<<4, dim3(512), 0, stream>>>(acc16, imp);
  // 6. mixed K quantization (+ per-row dequant slice norm)
  k_quant_kmixed<<<TT, b256, 0, stream>>>(kbuf, imp, qkm, skv, kmn_row);
  k_redmax2<<<1, b256, 0, stream>>>(kmn_row, kmn_row, nbv + 2);
  // 7. attention pass 2 (dbuf, ones-MFMA l, diag-branch, exp2) + combine
  k_attn2<<<ga, b256, 0, stream>>>(q_hi, q_lo, qkm, skv, qvT, sv, nbv, ctx, lp2, Opart);
  k_attn2_combine<<<dim3(24,16), b256, 0, stream>>>(lp2, Opart, sv, ctx);
  // 8. output projection (int8 MFMA, 128x128/BK=64)
  k_rowquant8<<<TT, b256, 0, stream>>>(ctx, qctx, sctx);
  k_gemm8_one<<<dim3(EE/128, TT/128), b256, 0, stream>>>(
      qctx, sctx, qw4 + (size_t)3*EE*EE, sw + 3*EE, o_b, (float*)d_out);
}